// Round 9
// baseline (390.707 us; speedup 1.0000x reference)
//
#include <hip/hip_runtime.h>

#define B_ROWS 32768
#define D_NETS 16
#define MWH    1048576              // halfs per packed 1024x1024 layer
#define GW1OFF (3 * MWH)            // gW1 pack offset (halfs)
#define HPOFF  (GW1OFF + 16384)     // h-net pack offset (halfs)

typedef _Float16 half8 __attribute__((ext_vector_type(8)));
typedef _Float16 half4 __attribute__((ext_vector_type(4)));
typedef __attribute__((ext_vector_type(16))) float f32x16;

#define MFMA16 __builtin_amdgcn_mfma_f32_32x32x16_f16

// ---------------------------------------------------------------------------
// pack: all weights -> fp16, MFMA-fragment-linear packed (A-operand layout:
// lane = khalf*32 + (n&31), 8 consecutive k per lane).
// ---------------------------------------------------------------------------
__global__ void pack_f16(const float* __restrict__ gW1,
                         const float* __restrict__ gW2,
                         const float* __restrict__ gW3,
                         const float* __restrict__ gW4,
                         const float* __restrict__ hW2,
                         const float* __restrict__ hW3,
                         const float* __restrict__ hW4,
                         _Float16* __restrict__ ws) {
    const int p = blockIdx.x * 256 + threadIdx.x;
    const float* src;
    size_t dst;
    if (p < 393216) {                       // gW2/3/4: 3 x 131072 chunks
        const int lz = p >> 17;
        const int pl = p & 131071;
        const float* W = (lz == 0) ? gW2 : (lz == 1) ? gW3 : gW4;
        const int l = pl & 63, g = (pl >> 6) & 31, ks = pl >> 11;
        src = &W[(size_t)(g * 32 + (l & 31)) * 1024 + ks * 16 + (l >> 5) * 8];
        dst = (size_t)lz * MWH + (size_t)pl * 8;
    } else if (p < 395264) {                // gW1: 2048 chunks
        const int q = p - 393216;
        const int l = q & 63, g = q >> 6;
        src = &gW1[(g * 32 + (l & 31)) * 16 + (l >> 5) * 8];
        dst = GW1OFF + (size_t)q * 8;
    } else {                                // hW2/3/4: 24576 chunks
        const int q = p - 395264;
        const int l = q & 63;
        const int sub = (q >> 6) & 7;       // ks*2+g
        const int ks = sub >> 1, g = sub & 1;
        const int dL = q >> 9;              // d*3+L
        const int d = dL / 3, L = dL - d * 3;
        const float* W = (L == 0) ? hW2 : (L == 1) ? hW3 : hW4;
        src = &W[d * 4096 + (g * 32 + (l & 31)) * 64 + ks * 16 + (l >> 5) * 8];
        dst = HPOFF + (size_t)q * 8;
    }
    half8 v;
    #pragma unroll
    for (int kk = 0; kk < 8; ++kk) v[kk] = (_Float16)src[kk];
    *(half8*)&ws[dst] = v;
}

// ---------------------------------------------------------------------------
// h-network on MFMA (unchanged; small share of runtime).
// ---------------------------------------------------------------------------
__global__ __launch_bounds__(256, 4) void h_net_mfma(
    const float* __restrict__ x,
    const float* __restrict__ hW1, const float* __restrict__ hb1,
    const float* __restrict__ hb2, const float* __restrict__ hb3,
    const float* __restrict__ hb4,
    const float* __restrict__ hW5, const float* __restrict__ hb5,
    const _Float16* __restrict__ ws,
    float* __restrict__ out)
{
    __shared__ _Float16 sA[8192];
    __shared__ float s_w1[64], s_b1[64], s_bs[3][64], s_w5[64];

    const int t = threadIdx.x;
    const int d = blockIdx.y;
    const int row0 = blockIdx.x * 128;
    const int l = t & 63, wv = t >> 6;
    const int l31 = l & 31, lk = l >> 5;

    if (t < 64) {
        s_w1[t]    = hW1[d * 64 + t];
        s_b1[t]    = hb1[d * 64 + t];
        s_bs[0][t] = hb2[d * 64 + t];
        s_bs[1][t] = hb3[d * 64 + t];
        s_bs[2][t] = hb4[d * 64 + t];
        s_w5[t]    = hW5[d * 64 + t];
    }
    __syncthreads();

    {
        const int row = t >> 1, jh = t & 1, rg = row >> 5, r31 = row & 31;
        const float sv = x[(size_t)(row0 + row) * 32 + 16 + d];
        #pragma unroll
        for (int jj = 0; jj < 32; ++jj) {
            const int j = jh * 32 + jj;
            const float a = fmaxf(fmaf(sv, s_w1[j], s_b1[j]), 0.f);
            const int ks = j >> 4;
            const int li = ((((j >> 3) & 1) << 5) | r31) ^ (ks << 3);
            sA[((rg * 4 + ks) * 64 + li) * 8 + (j & 7)] = (_Float16)a;
        }
    }
    __syncthreads();

    const _Float16* hp = ws + HPOFF + (size_t)d * 3 * 4096;

    #pragma unroll 1
    for (int L = 0; L < 3; ++L) {
        const _Float16* W = hp + (size_t)L * 4096;
        half8 B[4][2], A[4];
        #pragma unroll
        for (int ks = 0; ks < 4; ++ks) {
            B[ks][0] = *(const half8*)&W[((ks * 2 + 0) * 64 + l) * 8];
            B[ks][1] = *(const half8*)&W[((ks * 2 + 1) * 64 + l) * 8];
            A[ks] = *(const half8*)&sA[((wv * 4 + ks) * 64 + (l ^ (ks << 3))) * 8];
        }
        f32x16 acc[2];
        #pragma unroll
        for (int nt = 0; nt < 2; ++nt) {
            const float bv = s_bs[L][nt * 32 + l31];
            #pragma unroll
            for (int r = 0; r < 16; ++r) acc[nt][r] = bv;
        }
        #pragma unroll
        for (int ks = 0; ks < 4; ++ks) {
            acc[0] = MFMA16(A[ks], B[ks][0], acc[0], 0, 0, 0);
            acc[1] = MFMA16(A[ks], B[ks][1], acc[1], 0, 0, 0);
        }
        __syncthreads();
        #pragma unroll
        for (int nt = 0; nt < 2; ++nt) {
            #pragma unroll
            for (int r = 0; r < 16; ++r) {
                const int r31 = (r & 3) + 8 * (r >> 2) + 4 * lk;
                const int col = nt * 32 + l31;
                const float v = fmaxf(acc[nt][r], 0.f);
                const int ks = col >> 4;
                const int li = ((((col >> 3) & 1) << 5) | r31) ^ (ks << 3);
                sA[((wv * 4 + ks) * 64 + li) * 8 + (col & 7)] = (_Float16)v;
            }
        }
        __syncthreads();
    }

    {
        const int row = t >> 1, jh = t & 1, rg = row >> 5, r31 = row & 31;
        float s = 0.f;
        #pragma unroll
        for (int ks2 = 0; ks2 < 2; ++ks2) {
            const int ks = jh * 2 + ks2;
            #pragma unroll
            for (int h2 = 0; h2 < 2; ++h2) {
                const int li = ((h2 << 5) | r31) ^ (ks << 3);
                half8 v = *(const half8*)&sA[((rg * 4 + ks) * 64 + li) * 8];
                const float* w = &s_w5[ks * 16 + h2 * 8];
                #pragma unroll
                for (int kk = 0; kk < 8; ++kk)
                    s = fmaf((float)v[kk], w[kk], s);
            }
        }
        s += __shfl_xor(s, 1);
        if (jh == 0) out[(size_t)(row0 + row) * 16 + d] = s + hb5[d];
    }
}

// ---------------------------------------------------------------------------
// g-network fused v4: 8 waves (512 thr), wave = 128n x 64rows, 4-deep B
// prefetch (global) + 4-deep A (LDS). acc[4][2] f32x16 = 128 AGPR;
// launch_bounds(512,2) -> 256-reg budget. W read once per block.
// Acts in LDS pack sA[rg][ksn][lane=kh*32|row31][8k], conflict-free b128.
// ---------------------------------------------------------------------------
__global__ __launch_bounds__(512, 2) void g_fused_v4(
    const float* __restrict__ x,
    const _Float16* __restrict__ ws,
    const float* __restrict__ gb1, const float* __restrict__ gb2,
    const float* __restrict__ gb3, const float* __restrict__ gb4,
    const float* __restrict__ gW5, const float* __restrict__ gb5,
    float* __restrict__ out)
{
    __shared__ _Float16 sA[65536];     // 128 KiB act pack
    __shared__ float s_w5f[1024];
    __shared__ float s_red[512];

    const int t = threadIdx.x;
    const int l = t & 63, wv = t >> 6;      // 8 waves
    const int l31 = l & 31, lk = l >> 5;
    const int n0 = wv * 128;
    const int row0 = blockIdx.x * 64;

    s_w5f[t] = gW5[t];
    s_w5f[t + 512] = gW5[t + 512];

    f32x16 acc[4][2];   // [nt][rg]; n = n0+nt*32+(r&3)+8*(r>>2)+4*lk, row=rg*32+l31

#define G_EPI()                                                              \
    {                                                                        \
        _Pragma("unroll")                                                    \
        for (int nt = 0; nt < 4; ++nt) {                                     \
            _Pragma("unroll")                                                \
            for (int rg = 0; rg < 2; ++rg) {                                 \
                _Pragma("unroll")                                            \
                for (int q = 0; q < 4; ++q) {                                \
                    half4 v;                                                 \
                    _Pragma("unroll")                                        \
                    for (int j = 0; j < 4; ++j)                              \
                        v[j] = (_Float16)fmaxf(acc[nt][rg][q * 4 + j], 0.f); \
                    const int ksn = wv * 8 + nt * 2 + (q >> 1);              \
                    const int li  = ((q & 1) << 5) | l31;                    \
                    *(half4*)&sA[((rg * 64 + ksn) * 64 + li) * 8 + lk * 4] = v; \
                }                                                            \
            }                                                                \
        }                                                                    \
    }

    // ---- layer 1 (K=16) ----
    {
        half8 xb[2];
        #pragma unroll
        for (int rg = 0; rg < 2; ++rg) {
            const float* xp = &x[(size_t)(row0 + rg * 32 + l31) * 32 + lk * 8];
            #pragma unroll
            for (int kk = 0; kk < 8; ++kk) xb[rg][kk] = (_Float16)xp[kk];
        }
        #pragma unroll
        for (int nt = 0; nt < 4; ++nt) {
            half8 wb = *(const half8*)&ws[GW1OFF + ((wv * 4 + nt) * 64 + l) * 8];
            #pragma unroll
            for (int rg = 0; rg < 2; ++rg) {
                #pragma unroll
                for (int r = 0; r < 16; ++r)
                    acc[nt][rg][r] =
                        gb1[n0 + nt * 32 + (r & 3) + 8 * (r >> 2) + 4 * lk];
                acc[nt][rg] = MFMA16(wb, xb[rg], acc[nt][rg], 0, 0, 0);
            }
        }
    }
    G_EPI();
    __syncthreads();

    // ---- layers 2..4 ----
#define G_LA(ks, A_)                                                         \
    { A_[0] = *(const half8*)&sA[((ks) * 64 + l) * 8];                       \
      A_[1] = *(const half8*)&sA[((64 + (ks)) * 64 + l) * 8]; }
#define G_LB(ks, B_)                                                         \
    { const int _o = (ks) * 16384 + wv * 2048 + l * 8;                       \
      B_[0] = *(const half8*)&W[_o];                                         \
      B_[1] = *(const half8*)&W[_o + 512];                                   \
      B_[2] = *(const half8*)&W[_o + 1024];                                  \
      B_[3] = *(const half8*)&W[_o + 1536]; }
#define G_MM(A_, B_)                                                         \
    { _Pragma("unroll")                                                      \
      for (int nt = 0; nt < 4; ++nt) {                                       \
          acc[nt][0] = MFMA16(B_[nt], A_[0], acc[nt][0], 0, 0, 0);           \
          acc[nt][1] = MFMA16(B_[nt], A_[1], acc[nt][1], 0, 0, 0);           \
      } }

    #pragma unroll 1
    for (int L = 0; L < 3; ++L) {
        const _Float16* W = ws + (size_t)L * MWH;
        const float* gbL = (L == 0) ? gb2 : (L == 1) ? gb3 : gb4;

        half8 A0[2], A1[2], A2[2], A3[2];
        half8 B0[4], B1[4], B2[4], B3[4];

        G_LB(0, B0); G_LB(1, B1); G_LB(2, B2);
        G_LA(0, A0); G_LA(1, A1);

        #pragma unroll
        for (int nt = 0; nt < 4; ++nt)
            #pragma unroll
            for (int rg = 0; rg < 2; ++rg)
                #pragma unroll
                for (int r = 0; r < 16; ++r)
                    acc[nt][rg][r] =
                        gbL[n0 + nt * 32 + (r & 3) + 8 * (r >> 2) + 4 * lk];

        #pragma unroll 1
        for (int ks = 0; ks < 64; ks += 4) {
            int s2 = ks + 2; s2 = s2 > 63 ? 63 : s2;
            int s3 = ks + 3; s3 = s3 > 63 ? 63 : s3;
            int s4 = ks + 4; s4 = s4 > 63 ? 63 : s4;
            int s5 = ks + 5; s5 = s5 > 63 ? 63 : s5;
            int s6 = ks + 6; s6 = s6 > 63 ? 63 : s6;

            G_LB(s3, B3);  G_LA(s2, A2);  G_MM(A0, B0);
            G_LB(s4, B0);  G_LA(s3, A3);  G_MM(A1, B1);
            G_LB(s5, B1);  G_LA(s4, A0);  G_MM(A2, B2);
            G_LB(s6, B2);  G_LA(s5, A1);  G_MM(A3, B3);
        }

        __syncthreads();     // all waves done reading sA
        G_EPI();
        __syncthreads();     // sA ready for next layer
    }
#undef G_LA
#undef G_LB
#undef G_MM
#undef G_EPI

    // ---- layer 5: out_g[row] = act . gW5 + gb5 ----
    {
        const int row = l;             // 0..63
        const int rg5 = row >> 5, r31 = row & 31;
        const int c = wv;              // 0..7: 128-n chunk
        float s = 0.f;
        #pragma unroll
        for (int q = 0; q < 8; ++q) {
            const int ksn = c * 8 + q;
            #pragma unroll
            for (int kh = 0; kh < 2; ++kh) {
                half8 v = *(const half8*)&sA[((rg5 * 64 + ksn) * 64 +
                                             ((kh << 5) | r31)) * 8];
                const float* w = &s_w5f[ksn * 16 + kh * 8];
                #pragma unroll
                for (int kk = 0; kk < 8; ++kk)
                    s = fmaf((float)v[kk], w[kk], s);
            }
        }
        s_red[t] = s;
    }
    __syncthreads();
    if (t < 64) {
        float s = gb5[0];
        #pragma unroll
        for (int c = 0; c < 8; ++c) s += s_red[c * 64 + t];
        out[(size_t)B_ROWS * D_NETS + row0 + t] = s;
    }
}

extern "C" void kernel_launch(void* const* d_in, const int* in_sizes, int n_in,
                              void* d_out, int out_size, void* d_ws, size_t ws_size,
                              hipStream_t stream) {
    (void)in_sizes; (void)n_in; (void)out_size; (void)ws_size;

    const float* x   = (const float*)d_in[0];
    const float* hW1 = (const float*)d_in[1];
    const float* hb1 = (const float*)d_in[2];
    const float* hW2 = (const float*)d_in[3];
    const float* hb2 = (const float*)d_in[4];
    const float* hW3 = (const float*)d_in[5];
    const float* hb3 = (const float*)d_in[6];
    const float* hW4 = (const float*)d_in[7];
    const float* hb4 = (const float*)d_in[8];
    const float* hW5 = (const float*)d_in[9];
    const float* hb5 = (const float*)d_in[10];
    const float* gW1 = (const float*)d_in[11];
    const float* gb1 = (const float*)d_in[12];
    const float* gW2 = (const float*)d_in[13];
    const float* gb2 = (const float*)d_in[14];
    const float* gW3 = (const float*)d_in[15];
    const float* gb3 = (const float*)d_in[16];
    const float* gW4 = (const float*)d_in[17];
    const float* gb4 = (const float*)d_in[18];
    const float* gW5 = (const float*)d_in[19];
    const float* gb5 = (const float*)d_in[20];
    float* out = (float*)d_out;
    _Float16* wsh = (_Float16*)d_ws;

    pack_f16<<<1640, 256, 0, stream>>>(gW1, gW2, gW3, gW4, hW2, hW3, hW4, wsh);

    dim3 gh(B_ROWS / 128, D_NETS);
    h_net_mfma<<<gh, 256, 0, stream>>>(x, hW1, hb1, hb2, hb3, hb4,
                                       hW5, hb5, wsh, out);

    g_fused_v4<<<B_ROWS / 64, 512, 0, stream>>>(x, wsh, gb1, gb2, gb3, gb4,
                                                gW5, gb5, out);
}

// Round 10
// 342.497 us; speedup vs baseline: 1.1408x; 1.1408x over previous
//
#include <hip/hip_runtime.h>

#define B_ROWS 32768
#define D_NETS 16
#define MWH    1048576              // halfs per packed 1024x1024 layer
#define GW1OFF (3 * MWH)            // gW1 pack offset (halfs)
#define HPOFF  (GW1OFF + 16384)     // h-net pack offset (halfs)

typedef _Float16 half8 __attribute__((ext_vector_type(8)));
typedef _Float16 half4 __attribute__((ext_vector_type(4)));
typedef __attribute__((ext_vector_type(16))) float f32x16;

#define MFMA16 __builtin_amdgcn_mfma_f32_32x32x16_f16

// ---------------------------------------------------------------------------
// pack: all weights -> fp16, MFMA-fragment-linear packed (A-operand layout:
// lane = khalf*32 + (n&31), 8 consecutive k per lane).
// ---------------------------------------------------------------------------
__global__ void pack_f16(const float* __restrict__ gW1,
                         const float* __restrict__ gW2,
                         const float* __restrict__ gW3,
                         const float* __restrict__ gW4,
                         const float* __restrict__ hW2,
                         const float* __restrict__ hW3,
                         const float* __restrict__ hW4,
                         _Float16* __restrict__ ws) {
    const int p = blockIdx.x * 256 + threadIdx.x;
    const float* src;
    size_t dst;
    if (p < 393216) {                       // gW2/3/4: 3 x 131072 chunks
        const int lz = p >> 17;
        const int pl = p & 131071;
        const float* W = (lz == 0) ? gW2 : (lz == 1) ? gW3 : gW4;
        const int l = pl & 63, g = (pl >> 6) & 31, ks = pl >> 11;
        src = &W[(size_t)(g * 32 + (l & 31)) * 1024 + ks * 16 + (l >> 5) * 8];
        dst = (size_t)lz * MWH + (size_t)pl * 8;
    } else if (p < 395264) {                // gW1: 2048 chunks
        const int q = p - 393216;
        const int l = q & 63, g = q >> 6;
        src = &gW1[(g * 32 + (l & 31)) * 16 + (l >> 5) * 8];
        dst = GW1OFF + (size_t)q * 8;
    } else {                                // hW2/3/4: 24576 chunks
        const int q = p - 395264;
        const int l = q & 63;
        const int sub = (q >> 6) & 7;       // ks*2+g
        const int ks = sub >> 1, g = sub & 1;
        const int dL = q >> 9;              // d*3+L
        const int d = dL / 3, L = dL - d * 3;
        const float* W = (L == 0) ? hW2 : (L == 1) ? hW3 : hW4;
        src = &W[d * 4096 + (g * 32 + (l & 31)) * 64 + ks * 16 + (l >> 5) * 8];
        dst = HPOFF + (size_t)q * 8;
    }
    half8 v;
    #pragma unroll
    for (int kk = 0; kk < 8; ++kk) v[kk] = (_Float16)src[kk];
    *(half8*)&ws[dst] = v;
}

// ---------------------------------------------------------------------------
// h-network on MFMA (unchanged; small share of runtime).
// ---------------------------------------------------------------------------
__global__ __launch_bounds__(256, 4) void h_net_mfma(
    const float* __restrict__ x,
    const float* __restrict__ hW1, const float* __restrict__ hb1,
    const float* __restrict__ hb2, const float* __restrict__ hb3,
    const float* __restrict__ hb4,
    const float* __restrict__ hW5, const float* __restrict__ hb5,
    const _Float16* __restrict__ ws,
    float* __restrict__ out)
{
    __shared__ _Float16 sA[8192];
    __shared__ float s_w1[64], s_b1[64], s_bs[3][64], s_w5[64];

    const int t = threadIdx.x;
    const int d = blockIdx.y;
    const int row0 = blockIdx.x * 128;
    const int l = t & 63, wv = t >> 6;
    const int l31 = l & 31, lk = l >> 5;

    if (t < 64) {
        s_w1[t]    = hW1[d * 64 + t];
        s_b1[t]    = hb1[d * 64 + t];
        s_bs[0][t] = hb2[d * 64 + t];
        s_bs[1][t] = hb3[d * 64 + t];
        s_bs[2][t] = hb4[d * 64 + t];
        s_w5[t]    = hW5[d * 64 + t];
    }
    __syncthreads();

    {
        const int row = t >> 1, jh = t & 1, rg = row >> 5, r31 = row & 31;
        const float sv = x[(size_t)(row0 + row) * 32 + 16 + d];
        #pragma unroll
        for (int jj = 0; jj < 32; ++jj) {
            const int j = jh * 32 + jj;
            const float a = fmaxf(fmaf(sv, s_w1[j], s_b1[j]), 0.f);
            const int ks = j >> 4;
            const int li = ((((j >> 3) & 1) << 5) | r31) ^ (ks << 3);
            sA[((rg * 4 + ks) * 64 + li) * 8 + (j & 7)] = (_Float16)a;
        }
    }
    __syncthreads();

    const _Float16* hp = ws + HPOFF + (size_t)d * 3 * 4096;

    #pragma unroll 1
    for (int L = 0; L < 3; ++L) {
        const _Float16* W = hp + (size_t)L * 4096;
        half8 B[4][2], A[4];
        #pragma unroll
        for (int ks = 0; ks < 4; ++ks) {
            B[ks][0] = *(const half8*)&W[((ks * 2 + 0) * 64 + l) * 8];
            B[ks][1] = *(const half8*)&W[((ks * 2 + 1) * 64 + l) * 8];
            A[ks] = *(const half8*)&sA[((wv * 4 + ks) * 64 + (l ^ (ks << 3))) * 8];
        }
        f32x16 acc[2];
        #pragma unroll
        for (int nt = 0; nt < 2; ++nt) {
            const float bv = s_bs[L][nt * 32 + l31];
            #pragma unroll
            for (int r = 0; r < 16; ++r) acc[nt][r] = bv;
        }
        #pragma unroll
        for (int ks = 0; ks < 4; ++ks) {
            acc[0] = MFMA16(A[ks], B[ks][0], acc[0], 0, 0, 0);
            acc[1] = MFMA16(A[ks], B[ks][1], acc[1], 0, 0, 0);
        }
        __syncthreads();
        #pragma unroll
        for (int nt = 0; nt < 2; ++nt) {
            #pragma unroll
            for (int r = 0; r < 16; ++r) {
                const int r31 = (r & 3) + 8 * (r >> 2) + 4 * lk;
                const int col = nt * 32 + l31;
                const float v = fmaxf(acc[nt][r], 0.f);
                const int ks = col >> 4;
                const int li = ((((col >> 3) & 1) << 5) | r31) ^ (ks << 3);
                sA[((wv * 4 + ks) * 64 + li) * 8 + (col & 7)] = (_Float16)v;
            }
        }
        __syncthreads();
    }

    {
        const int row = t >> 1, jh = t & 1, rg = row >> 5, r31 = row & 31;
        float s = 0.f;
        #pragma unroll
        for (int ks2 = 0; ks2 < 2; ++ks2) {
            const int ks = jh * 2 + ks2;
            #pragma unroll
            for (int h2 = 0; h2 < 2; ++h2) {
                const int li = ((h2 << 5) | r31) ^ (ks << 3);
                half8 v = *(const half8*)&sA[((rg * 4 + ks) * 64 + li) * 8];
                const float* w = &s_w5[ks * 16 + h2 * 8];
                #pragma unroll
                for (int kk = 0; kk < 8; ++kk)
                    s = fmaf((float)v[kk], w[kk], s);
            }
        }
        s += __shfl_xor(s, 1);
        if (jh == 0) out[(size_t)(row0 + row) * 16 + d] = s + hb5[d];
    }
}

// ---------------------------------------------------------------------------
// g-network fused v5: v3 geometry (16 waves, wave = 64n x 64rows, 2-deep),
// scheduling attacked: (1) K-loop FULLY UNROLLED (no back-edges -> fine
// counted waitcnts, immediate ds offsets); (2) cross-layer B prefetch (tail
// slots wrap to next layer's W -> B0..B2 hot at every layer start);
// (3) s_setprio(1) around each 4-MFMA cluster (T5).
// ---------------------------------------------------------------------------
__global__ __launch_bounds__(1024, 4) void g_fused_v5(
    const float* __restrict__ x,
    const _Float16* __restrict__ ws,
    const float* __restrict__ gb1, const float* __restrict__ gb2,
    const float* __restrict__ gb3, const float* __restrict__ gb4,
    const float* __restrict__ gW5, const float* __restrict__ gb5,
    float* __restrict__ out)
{
    __shared__ _Float16 sA[65536];     // 128 KiB act pack
    __shared__ float s_w5f[1024];
    __shared__ float s_red[1024];

    const int t = threadIdx.x;
    const int l = t & 63, wv = t >> 6;
    const int l31 = l & 31, lk = l >> 5;
    const int n0 = wv * 64;
    const int row0 = blockIdx.x * 64;

    s_w5f[t] = gW5[t];

    f32x16 acc[2][2];   // [nt][rg]
    half8 A0[2], A1[2], A2[2], A3[2];
    half8 B0[2], B1[2], B2[2], B3[2];

#define G_LBP(W_, ks, B_)                                                    \
    { const int _o = (ks) * 16384 + wv * 1024 + l * 8;                       \
      B_[0] = *(const half8*)&W_[_o];                                        \
      B_[1] = *(const half8*)&W_[_o + 512]; }

    // issue first B tiles of gW2 immediately (fly under layer 1)
    G_LBP(ws, 0, B0);
    G_LBP(ws, 1, B1);
    G_LBP(ws, 2, B2);

#define G_EPI()                                                              \
    {                                                                        \
        _Pragma("unroll")                                                    \
        for (int nt = 0; nt < 2; ++nt) {                                     \
            _Pragma("unroll")                                                \
            for (int rg = 0; rg < 2; ++rg) {                                 \
                _Pragma("unroll")                                            \
                for (int q = 0; q < 4; ++q) {                                \
                    half4 v;                                                 \
                    _Pragma("unroll")                                        \
                    for (int j = 0; j < 4; ++j)                              \
                        v[j] = (_Float16)fmaxf(acc[nt][rg][q * 4 + j], 0.f); \
                    const int ksn = wv * 4 + nt * 2 + (q >> 1);              \
                    const int li  = ((q & 1) << 5) | l31;                    \
                    *(half4*)&sA[((rg * 64 + ksn) * 64 + li) * 8 + lk * 4] = v; \
                }                                                            \
            }                                                                \
        }                                                                    \
    }

    // ---- layer 1 (K=16) ----
    {
        half8 xb[2];
        #pragma unroll
        for (int rg = 0; rg < 2; ++rg) {
            const float* xp = &x[(size_t)(row0 + rg * 32 + l31) * 32 + lk * 8];
            #pragma unroll
            for (int kk = 0; kk < 8; ++kk) xb[rg][kk] = (_Float16)xp[kk];
        }
        #pragma unroll
        for (int nt = 0; nt < 2; ++nt) {
            half8 wb = *(const half8*)&ws[GW1OFF + ((wv * 2 + nt) * 64 + l) * 8];
            #pragma unroll
            for (int rg = 0; rg < 2; ++rg) {
                #pragma unroll
                for (int r = 0; r < 16; ++r)
                    acc[nt][rg][r] =
                        gb1[n0 + nt * 32 + (r & 3) + 8 * (r >> 2) + 4 * lk];
                acc[nt][rg] = MFMA16(wb, xb[rg], acc[nt][rg], 0, 0, 0);
            }
        }
    }
    G_EPI();
    __syncthreads();

    // ---- layers 2..4 (fully-unrolled K loop, wrap-prefetch, setprio) ----
#define G_LA(ks, A_)                                                         \
    { A_[0] = *(const half8*)&sA[((ks) * 64 + l) * 8];                       \
      A_[1] = *(const half8*)&sA[((64 + (ks)) * 64 + l) * 8]; }
#define G_LAC(ks, A_)  { if ((ks) <= 63) G_LA(ks, A_) }
#define G_LBX(s, B_)                                                         \
    { if ((s) > 63) { G_LBP(Wn, (s) & 63, B_) } else { G_LBP(W, s, B_) } }
#define G_MM(A_, B_)                                                         \
    { __builtin_amdgcn_s_setprio(1);                                         \
      acc[0][0] = MFMA16(B_[0], A_[0], acc[0][0], 0, 0, 0);                  \
      acc[0][1] = MFMA16(B_[0], A_[1], acc[0][1], 0, 0, 0);                  \
      acc[1][0] = MFMA16(B_[1], A_[0], acc[1][0], 0, 0, 0);                  \
      acc[1][1] = MFMA16(B_[1], A_[1], acc[1][1], 0, 0, 0);                  \
      __builtin_amdgcn_s_setprio(0); }

    #pragma unroll 1
    for (int L = 0; L < 3; ++L) {
        const _Float16* W  = ws + (size_t)L * MWH;
        const _Float16* Wn = ws + (size_t)(L < 2 ? L + 1 : L) * MWH;
        const float* gbL = (L == 0) ? gb2 : (L == 1) ? gb3 : gb4;

        G_LA(0, A0);
        G_LA(1, A1);

        #pragma unroll
        for (int nt = 0; nt < 2; ++nt)
            #pragma unroll
            for (int rg = 0; rg < 2; ++rg)
                #pragma unroll
                for (int r = 0; r < 16; ++r)
                    acc[nt][rg][r] =
                        gbL[n0 + nt * 32 + (r & 3) + 8 * (r >> 2) + 4 * lk];

        #pragma unroll
        for (int ks = 0; ks < 64; ks += 4) {
            G_LBX(ks + 3, B3);  G_LAC(ks + 2, A2);  G_MM(A0, B0);
            G_LBX(ks + 4, B0);  G_LAC(ks + 3, A3);  G_MM(A1, B1);
            G_LBX(ks + 5, B1);  G_LAC(ks + 4, A0);  G_MM(A2, B2);
            G_LBX(ks + 6, B2);  G_LAC(ks + 5, A1);  G_MM(A3, B3);
        }
        // tail wrap leaves B0,B1,B2 = next layer's ks 0,1,2

        __syncthreads();     // all waves done reading sA
        G_EPI();
        __syncthreads();     // sA ready for next layer
    }
#undef G_LA
#undef G_LAC
#undef G_LBX
#undef G_LBP
#undef G_MM
#undef G_EPI

    // ---- layer 5: out_g[row] = act . gW5 + gb5 ----
    {
        const int row = t & 63;
        const int rg5 = row >> 5, r31 = row & 31;
        const int c = t >> 6;          // 0..15: 64-n chunk
        float s = 0.f;
        #pragma unroll
        for (int q = 0; q < 4; ++q) {
            #pragma unroll
            for (int kh = 0; kh < 2; ++kh) {
                half8 v = *(const half8*)&sA[((rg5 * 64 + c * 4 + q) * 64 +
                                             ((kh << 5) | r31)) * 8];
                const float* w = &s_w5f[(c * 4 + q) * 16 + kh * 8];
                #pragma unroll
                for (int kk = 0; kk < 8; ++kk)
                    s = fmaf((float)v[kk], w[kk], s);
            }
        }
        s_red[t] = s;
    }
    __syncthreads();
    if (t < 64) {
        float s = gb5[0];
        #pragma unroll
        for (int c = 0; c < 16; ++c) s += s_red[c * 64 + t];
        out[(size_t)B_ROWS * D_NETS + row0 + t] = s;
    }
}

extern "C" void kernel_launch(void* const* d_in, const int* in_sizes, int n_in,
                              void* d_out, int out_size, void* d_ws, size_t ws_size,
                              hipStream_t stream) {
    (void)in_sizes; (void)n_in; (void)out_size; (void)ws_size;

    const float* x   = (const float*)d_in[0];
    const float* hW1 = (const float*)d_in[1];
    const float* hb1 = (const float*)d_in[2];
    const float* hW2 = (const float*)d_in[3];
    const float* hb2 = (const float*)d_in[4];
    const float* hW3 = (const float*)d_in[5];
    const float* hb3 = (const float*)d_in[6];
    const float* hW4 = (const float*)d_in[7];
    const float* hb4 = (const float*)d_in[8];
    const float* hW5 = (const float*)d_in[9];
    const float* hb5 = (const float*)d_in[10];
    const float* gW1 = (const float*)d_in[11];
    const float* gb1 = (const float*)d_in[12];
    const float* gW2 = (const float*)d_in[13];
    const float* gb2 = (const float*)d_in[14];
    const float* gW3 = (const float*)d_in[15];
    const float* gb3 = (const float*)d_in[16];
    const float* gW4 = (const float*)d_in[17];
    const float* gb4 = (const float*)d_in[18];
    const float* gW5 = (const float*)d_in[19];
    const float* gb5 = (const float*)d_in[20];
    float* out = (float*)d_out;
    _Float16* wsh = (_Float16*)d_ws;

    pack_f16<<<1640, 256, 0, stream>>>(gW1, gW2, gW3, gW4, hW2, hW3, hW4, wsh);

    dim3 gh(B_ROWS / 128, D_NETS);
    h_net_mfma<<<gh, 256, 0, stream>>>(x, hW1, hb1, hb2, hb3, hb4,
                                       hW5, hb5, wsh, out);

    g_fused_v5<<<B_ROWS / 64, 1024, 0, stream>>>(x, wsh, gb1, gb2, gb3, gb4,
                                                 gW5, gb5, out);
}

// Round 11
// 265.026 us; speedup vs baseline: 1.4742x; 1.2923x over previous
//
#include <hip/hip_runtime.h>

#define B_ROWS 32768
#define D_NETS 16
#define MWH    1048576              // halfs per packed 1024x1024 layer
#define GW1OFF (3 * MWH)            // gW1 pack offset (halfs)
#define HPOFF  (GW1OFF + 16384)     // h-net pack offset (halfs)

typedef _Float16 half8 __attribute__((ext_vector_type(8)));
typedef _Float16 half4 __attribute__((ext_vector_type(4)));
typedef __attribute__((ext_vector_type(16))) float f32x16;

#define MFMA16 __builtin_amdgcn_mfma_f32_32x32x16_f16

// ---------------------------------------------------------------------------
// pack: all weights -> fp16, MFMA-fragment-linear packed (A-operand layout:
// lane = khalf*32 + (n&31), 8 consecutive k per lane).
// ---------------------------------------------------------------------------
__global__ void pack_f16(const float* __restrict__ gW1,
                         const float* __restrict__ gW2,
                         const float* __restrict__ gW3,
                         const float* __restrict__ gW4,
                         const float* __restrict__ hW2,
                         const float* __restrict__ hW3,
                         const float* __restrict__ hW4,
                         _Float16* __restrict__ ws) {
    const int p = blockIdx.x * 256 + threadIdx.x;
    const float* src;
    size_t dst;
    if (p < 393216) {                       // gW2/3/4: 3 x 131072 chunks
        const int lz = p >> 17;
        const int pl = p & 131071;
        const float* W = (lz == 0) ? gW2 : (lz == 1) ? gW3 : gW4;
        const int l = pl & 63, g = (pl >> 6) & 31, ks = pl >> 11;
        src = &W[(size_t)(g * 32 + (l & 31)) * 1024 + ks * 16 + (l >> 5) * 8];
        dst = (size_t)lz * MWH + (size_t)pl * 8;
    } else if (p < 395264) {                // gW1: 2048 chunks
        const int q = p - 393216;
        const int l = q & 63, g = q >> 6;
        src = &gW1[(g * 32 + (l & 31)) * 16 + (l >> 5) * 8];
        dst = GW1OFF + (size_t)q * 8;
    } else {                                // hW2/3/4: 24576 chunks
        const int q = p - 395264;
        const int l = q & 63;
        const int sub = (q >> 6) & 7;       // ks*2+g
        const int ks = sub >> 1, g = sub & 1;
        const int dL = q >> 9;              // d*3+L
        const int d = dL / 3, L = dL - d * 3;
        const float* W = (L == 0) ? hW2 : (L == 1) ? hW3 : hW4;
        src = &W[d * 4096 + (g * 32 + (l & 31)) * 64 + ks * 16 + (l >> 5) * 8];
        dst = HPOFF + (size_t)q * 8;
    }
    half8 v;
    #pragma unroll
    for (int kk = 0; kk < 8; ++kk) v[kk] = (_Float16)src[kk];
    *(half8*)&ws[dst] = v;
}

// ---------------------------------------------------------------------------
// h-network on MFMA (unchanged; small share of runtime).
// ---------------------------------------------------------------------------
__global__ __launch_bounds__(256, 4) void h_net_mfma(
    const float* __restrict__ x,
    const float* __restrict__ hW1, const float* __restrict__ hb1,
    const float* __restrict__ hb2, const float* __restrict__ hb3,
    const float* __restrict__ hb4,
    const float* __restrict__ hW5, const float* __restrict__ hb5,
    const _Float16* __restrict__ ws,
    float* __restrict__ out)
{
    __shared__ _Float16 sA[8192];
    __shared__ float s_w1[64], s_b1[64], s_bs[3][64], s_w5[64];

    const int t = threadIdx.x;
    const int d = blockIdx.y;
    const int row0 = blockIdx.x * 128;
    const int l = t & 63, wv = t >> 6;
    const int l31 = l & 31, lk = l >> 5;

    if (t < 64) {
        s_w1[t]    = hW1[d * 64 + t];
        s_b1[t]    = hb1[d * 64 + t];
        s_bs[0][t] = hb2[d * 64 + t];
        s_bs[1][t] = hb3[d * 64 + t];
        s_bs[2][t] = hb4[d * 64 + t];
        s_w5[t]    = hW5[d * 64 + t];
    }
    __syncthreads();

    {
        const int row = t >> 1, jh = t & 1, rg = row >> 5, r31 = row & 31;
        const float sv = x[(size_t)(row0 + row) * 32 + 16 + d];
        #pragma unroll
        for (int jj = 0; jj < 32; ++jj) {
            const int j = jh * 32 + jj;
            const float a = fmaxf(fmaf(sv, s_w1[j], s_b1[j]), 0.f);
            const int ks = j >> 4;
            const int li = ((((j >> 3) & 1) << 5) | r31) ^ (ks << 3);
            sA[((rg * 4 + ks) * 64 + li) * 8 + (j & 7)] = (_Float16)a;
        }
    }
    __syncthreads();

    const _Float16* hp = ws + HPOFF + (size_t)d * 3 * 4096;

    #pragma unroll 1
    for (int L = 0; L < 3; ++L) {
        const _Float16* W = hp + (size_t)L * 4096;
        half8 B[4][2], A[4];
        #pragma unroll
        for (int ks = 0; ks < 4; ++ks) {
            B[ks][0] = *(const half8*)&W[((ks * 2 + 0) * 64 + l) * 8];
            B[ks][1] = *(const half8*)&W[((ks * 2 + 1) * 64 + l) * 8];
            A[ks] = *(const half8*)&sA[((wv * 4 + ks) * 64 + (l ^ (ks << 3))) * 8];
        }
        f32x16 acc[2];
        #pragma unroll
        for (int nt = 0; nt < 2; ++nt) {
            const float bv = s_bs[L][nt * 32 + l31];
            #pragma unroll
            for (int r = 0; r < 16; ++r) acc[nt][r] = bv;
        }
        #pragma unroll
        for (int ks = 0; ks < 4; ++ks) {
            acc[0] = MFMA16(A[ks], B[ks][0], acc[0], 0, 0, 0);
            acc[1] = MFMA16(A[ks], B[ks][1], acc[1], 0, 0, 0);
        }
        __syncthreads();
        #pragma unroll
        for (int nt = 0; nt < 2; ++nt) {
            #pragma unroll
            for (int r = 0; r < 16; ++r) {
                const int r31 = (r & 3) + 8 * (r >> 2) + 4 * lk;
                const int col = nt * 32 + l31;
                const float v = fmaxf(acc[nt][r], 0.f);
                const int ks = col >> 4;
                const int li = ((((col >> 3) & 1) << 5) | r31) ^ (ks << 3);
                sA[((wv * 4 + ks) * 64 + li) * 8 + (col & 7)] = (_Float16)v;
            }
        }
        __syncthreads();
    }

    {
        const int row = t >> 1, jh = t & 1, rg = row >> 5, r31 = row & 31;
        float s = 0.f;
        #pragma unroll
        for (int ks2 = 0; ks2 < 2; ++ks2) {
            const int ks = jh * 2 + ks2;
            #pragma unroll
            for (int h2 = 0; h2 < 2; ++h2) {
                const int li = ((h2 << 5) | r31) ^ (ks << 3);
                half8 v = *(const half8*)&sA[((rg * 4 + ks) * 64 + li) * 8];
                const float* w = &s_w5[ks * 16 + h2 * 8];
                #pragma unroll
                for (int kk = 0; kk < 8; ++kk)
                    s = fmaf((float)v[kk], w[kk], s);
            }
        }
        s += __shfl_xor(s, 1);
        if (jh == 0) out[(size_t)(row0 + row) * 16 + d] = s + hb5[d];
    }
}

// ---------------------------------------------------------------------------
// g-network fused v6 = v3 (proven 224 us) + register-neutral additions only:
// (1) s_setprio(1/0) around each 4-MFMA cluster (T5; barrier-free K-loop has
//     wave role diversity -> arbitration has something to do);
// (2) bias tables preloaded to LDS (kills 192 divergent global loads/wave).
// Geometry identical: 16 waves, wave = 64n x 64rows, 2-deep pipeline,
// 64 VGPR + 64 AGPR (exactly at the 4-wave/SIMD 128-reg cap).
// ---------------------------------------------------------------------------
__global__ __launch_bounds__(1024, 4) void g_fused_v6(
    const float* __restrict__ x,
    const _Float16* __restrict__ ws,
    const float* __restrict__ gb1, const float* __restrict__ gb2,
    const float* __restrict__ gb3, const float* __restrict__ gb4,
    const float* __restrict__ gW5, const float* __restrict__ gb5,
    float* __restrict__ out)
{
    __shared__ _Float16 sA[65536];     // 128 KiB act pack
    __shared__ float s_w5f[1024];
    __shared__ float s_red[1024];
    __shared__ float s_bias[3][1024];  // gb2/gb3/gb4

    const int t = threadIdx.x;
    const int l = t & 63, wv = t >> 6;
    const int l31 = l & 31, lk = l >> 5;
    const int n0 = wv * 64;
    const int row0 = blockIdx.x * 64;

    s_w5f[t] = gW5[t];
    s_bias[0][t] = gb2[t];
    s_bias[1][t] = gb3[t];
    s_bias[2][t] = gb4[t];

    f32x16 acc[2][2];   // [nt][rg]

#define G_EPI()                                                              \
    {                                                                        \
        _Pragma("unroll")                                                    \
        for (int nt = 0; nt < 2; ++nt) {                                     \
            _Pragma("unroll")                                                \
            for (int rg = 0; rg < 2; ++rg) {                                 \
                _Pragma("unroll")                                            \
                for (int q = 0; q < 4; ++q) {                                \
                    half4 v;                                                 \
                    _Pragma("unroll")                                        \
                    for (int j = 0; j < 4; ++j)                              \
                        v[j] = (_Float16)fmaxf(acc[nt][rg][q * 4 + j], 0.f); \
                    const int ksn = wv * 4 + nt * 2 + (q >> 1);              \
                    const int li  = ((q & 1) << 5) | l31;                    \
                    *(half4*)&sA[((rg * 64 + ksn) * 64 + li) * 8 + lk * 4] = v; \
                }                                                            \
            }                                                                \
        }                                                                    \
    }

    // ---- layer 1 (K=16) ----
    {
        half8 xb[2];
        #pragma unroll
        for (int rg = 0; rg < 2; ++rg) {
            const float* xp = &x[(size_t)(row0 + rg * 32 + l31) * 32 + lk * 8];
            #pragma unroll
            for (int kk = 0; kk < 8; ++kk) xb[rg][kk] = (_Float16)xp[kk];
        }
        #pragma unroll
        for (int nt = 0; nt < 2; ++nt) {
            half8 wb = *(const half8*)&ws[GW1OFF + ((wv * 2 + nt) * 64 + l) * 8];
            #pragma unroll
            for (int rg = 0; rg < 2; ++rg) {
                #pragma unroll
                for (int r = 0; r < 16; ++r)
                    acc[nt][rg][r] =
                        gb1[n0 + nt * 32 + (r & 3) + 8 * (r >> 2) + 4 * lk];
                acc[nt][rg] = MFMA16(wb, xb[rg], acc[nt][rg], 0, 0, 0);
            }
        }
    }
    G_EPI();
    __syncthreads();

    // ---- layers 2..4 (v3 2-deep loop + setprio) ----
#define G_LA(ks, A_)                                                         \
    { A_[0] = *(const half8*)&sA[((ks) * 64 + l) * 8];                       \
      A_[1] = *(const half8*)&sA[((64 + (ks)) * 64 + l) * 8]; }
#define G_LB(ks, B_)                                                         \
    { const int _o = (ks) * 16384 + wv * 1024 + l * 8;                       \
      B_[0] = *(const half8*)&W[_o];                                         \
      B_[1] = *(const half8*)&W[_o + 512]; }
#define G_MM(A_, B_)                                                         \
    { __builtin_amdgcn_s_setprio(1);                                         \
      acc[0][0] = MFMA16(B_[0], A_[0], acc[0][0], 0, 0, 0);                  \
      acc[0][1] = MFMA16(B_[0], A_[1], acc[0][1], 0, 0, 0);                  \
      acc[1][0] = MFMA16(B_[1], A_[0], acc[1][0], 0, 0, 0);                  \
      acc[1][1] = MFMA16(B_[1], A_[1], acc[1][1], 0, 0, 0);                  \
      __builtin_amdgcn_s_setprio(0); }

    #pragma unroll 1
    for (int L = 0; L < 3; ++L) {
        const _Float16* W = ws + (size_t)L * MWH;

        half8 A0[2], A1[2], B0[2], B1[2];
        G_LA(0, A0); G_LB(0, B0);
        G_LA(1, A1); G_LB(1, B1);

        #pragma unroll
        for (int nt = 0; nt < 2; ++nt)
            #pragma unroll
            for (int rg = 0; rg < 2; ++rg)
                #pragma unroll
                for (int r = 0; r < 16; ++r)
                    acc[nt][rg][r] =
                        s_bias[L][n0 + nt * 32 + (r & 3) + 8 * (r >> 2) + 4 * lk];

        #pragma unroll 1
        for (int ks = 0; ks < 64; ks += 2) {
            G_MM(A0, B0);
            if (ks + 2 < 64) { G_LA(ks + 2, A0); G_LB(ks + 2, B0); }
            G_MM(A1, B1);
            if (ks + 3 < 64) { G_LA(ks + 3, A1); G_LB(ks + 3, B1); }
        }

        __syncthreads();     // all waves done reading sA
        G_EPI();
        __syncthreads();     // sA ready for next layer
    }
#undef G_LA
#undef G_LB
#undef G_MM
#undef G_EPI

    // ---- layer 5: out_g[row] = act . gW5 + gb5 ----
    {
        const int row = t & 63;
        const int rg5 = row >> 5, r31 = row & 31;
        const int c = t >> 6;          // 0..15: 64-n chunk
        float s = 0.f;
        #pragma unroll
        for (int q = 0; q < 4; ++q) {
            #pragma unroll
            for (int kh = 0; kh < 2; ++kh) {
                half8 v = *(const half8*)&sA[((rg5 * 64 + c * 4 + q) * 64 +
                                             ((kh << 5) | r31)) * 8];
                const float* w = &s_w5f[(c * 4 + q) * 16 + kh * 8];
                #pragma unroll
                for (int kk = 0; kk < 8; ++kk)
                    s = fmaf((float)v[kk], w[kk], s);
            }
        }
        s_red[t] = s;
    }
    __syncthreads();
    if (t < 64) {
        float s = gb5[0];
        #pragma unroll
        for (int c = 0; c < 16; ++c) s += s_red[c * 64 + t];
        out[(size_t)B_ROWS * D_NETS + row0 + t] = s;
    }
}

extern "C" void kernel_launch(void* const* d_in, const int* in_sizes, int n_in,
                              void* d_out, int out_size, void* d_ws, size_t ws_size,
                              hipStream_t stream) {
    (void)in_sizes; (void)n_in; (void)out_size; (void)ws_size;

    const float* x   = (const float*)d_in[0];
    const float* hW1 = (const float*)d_in[1];
    const float* hb1 = (const float*)d_in[2];
    const float* hW2 = (const float*)d_in[3];
    const float* hb2 = (const float*)d_in[4];
    const float* hW3 = (const float*)d_in[5];
    const float* hb3 = (const float*)d_in[6];
    const float* hW4 = (const float*)d_in[7];
    const float* hb4 = (const float*)d_in[8];
    const float* hW5 = (const float*)d_in[9];
    const float* hb5 = (const float*)d_in[10];
    const float* gW1 = (const float*)d_in[11];
    const float* gb1 = (const float*)d_in[12];
    const float* gW2 = (const float*)d_in[13];
    const float* gb2 = (const float*)d_in[14];
    const float* gW3 = (const float*)d_in[15];
    const float* gb3 = (const float*)d_in[16];
    const float* gW4 = (const float*)d_in[17];
    const float* gb4 = (const float*)d_in[18];
    const float* gW5 = (const float*)d_in[19];
    const float* gb5 = (const float*)d_in[20];
    float* out = (float*)d_out;
    _Float16* wsh = (_Float16*)d_ws;

    pack_f16<<<1640, 256, 0, stream>>>(gW1, gW2, gW3, gW4, hW2, hW3, hW4, wsh);

    dim3 gh(B_ROWS / 128, D_NETS);
    h_net_mfma<<<gh, 256, 0, stream>>>(x, hW1, hb1, hb2, hb3, hb4,
                                       hW5, hb5, wsh, out);

    g_fused_v6<<<B_ROWS / 64, 1024, 0, stream>>>(x, wsh, gb1, gb2, gb3, gb4,
                                                 gW5, gb5, out);
}

// Round 12
// 251.786 us; speedup vs baseline: 1.5517x; 1.0526x over previous
//
#include <hip/hip_runtime.h>

#define B_ROWS 32768
#define D_NETS 16
#define MWH    1048576              // halfs per packed 1024x1024 layer
#define GW1OFF (3 * MWH)            // gW1 pack offset (halfs)
#define HPOFF  (GW1OFF + 16384)     // h-net pack offset (halfs)

typedef _Float16 half8 __attribute__((ext_vector_type(8)));
typedef _Float16 half4 __attribute__((ext_vector_type(4)));
typedef __attribute__((ext_vector_type(16))) float f32x16;

#define MFMA16 __builtin_amdgcn_mfma_f32_32x32x16_f16

// ---------------------------------------------------------------------------
// pack: all weights -> fp16, MFMA-fragment-linear packed (A-operand layout:
// lane = khalf*32 + (n&31), 8 consecutive k per lane).
// ---------------------------------------------------------------------------
__global__ void pack_f16(const float* __restrict__ gW1,
                         const float* __restrict__ gW2,
                         const float* __restrict__ gW3,
                         const float* __restrict__ gW4,
                         const float* __restrict__ hW2,
                         const float* __restrict__ hW3,
                         const float* __restrict__ hW4,
                         _Float16* __restrict__ ws) {
    const int p = blockIdx.x * 256 + threadIdx.x;
    const float* src;
    size_t dst;
    if (p < 393216) {                       // gW2/3/4: 3 x 131072 chunks
        const int lz = p >> 17;
        const int pl = p & 131071;
        const float* W = (lz == 0) ? gW2 : (lz == 1) ? gW3 : gW4;
        const int l = pl & 63, g = (pl >> 6) & 31, ks = pl >> 11;
        src = &W[(size_t)(g * 32 + (l & 31)) * 1024 + ks * 16 + (l >> 5) * 8];
        dst = (size_t)lz * MWH + (size_t)pl * 8;
    } else if (p < 395264) {                // gW1: 2048 chunks
        const int q = p - 393216;
        const int l = q & 63, g = q >> 6;
        src = &gW1[(g * 32 + (l & 31)) * 16 + (l >> 5) * 8];
        dst = GW1OFF + (size_t)q * 8;
    } else {                                // hW2/3/4: 24576 chunks
        const int q = p - 395264;
        const int l = q & 63;
        const int sub = (q >> 6) & 7;       // ks*2+g
        const int ks = sub >> 1, g = sub & 1;
        const int dL = q >> 9;              // d*3+L
        const int d = dL / 3, L = dL - d * 3;
        const float* W = (L == 0) ? hW2 : (L == 1) ? hW3 : hW4;
        src = &W[d * 4096 + (g * 32 + (l & 31)) * 64 + ks * 16 + (l >> 5) * 8];
        dst = HPOFF + (size_t)q * 8;
    }
    half8 v;
    #pragma unroll
    for (int kk = 0; kk < 8; ++kk) v[kk] = (_Float16)src[kk];
    *(half8*)&ws[dst] = v;
}

// ---------------------------------------------------------------------------
// g + h fused (v7). g part = proven v6 (226 us). h part: after out_g, wave
// wv computes h-net wv for the block's 64 rows, wave-locally, acts in that
// wave's 8 KB slice of sA (free after g L5). Same swapped-operand MFMA and
// q->(ks,kh,kk) epilogue mapping as g (proven). No extra barriers.
// ---------------------------------------------------------------------------
__global__ __launch_bounds__(1024, 4) void g_fused_v7(
    const float* __restrict__ x,
    const _Float16* __restrict__ ws,
    const float* __restrict__ gb1, const float* __restrict__ gb2,
    const float* __restrict__ gb3, const float* __restrict__ gb4,
    const float* __restrict__ gW5, const float* __restrict__ gb5,
    const float* __restrict__ hW1, const float* __restrict__ hb1,
    const float* __restrict__ hb2, const float* __restrict__ hb3,
    const float* __restrict__ hb4,
    const float* __restrict__ hW5, const float* __restrict__ hb5,
    float* __restrict__ out)
{
    __shared__ _Float16 sA[65536];     // 128 KiB act pack
    __shared__ float s_w5f[1024];
    __shared__ float s_red[1024];
    __shared__ float s_bias[3][1024];  // gb2/gb3/gb4

    const int t = threadIdx.x;
    const int l = t & 63, wv = t >> 6;
    const int l31 = l & 31, lk = l >> 5;
    const int n0 = wv * 64;
    const int row0 = blockIdx.x * 64;

    s_w5f[t] = gW5[t];
    s_bias[0][t] = gb2[t];
    s_bias[1][t] = gb3[t];
    s_bias[2][t] = gb4[t];

    f32x16 acc[2][2];   // [nt][rg]

#define G_EPI()                                                              \
    {                                                                        \
        _Pragma("unroll")                                                    \
        for (int nt = 0; nt < 2; ++nt) {                                     \
            _Pragma("unroll")                                                \
            for (int rg = 0; rg < 2; ++rg) {                                 \
                _Pragma("unroll")                                            \
                for (int q = 0; q < 4; ++q) {                                \
                    half4 v;                                                 \
                    _Pragma("unroll")                                        \
                    for (int j = 0; j < 4; ++j)                              \
                        v[j] = (_Float16)fmaxf(acc[nt][rg][q * 4 + j], 0.f); \
                    const int ksn = wv * 4 + nt * 2 + (q >> 1);              \
                    const int li  = ((q & 1) << 5) | l31;                    \
                    *(half4*)&sA[((rg * 64 + ksn) * 64 + li) * 8 + lk * 4] = v; \
                }                                                            \
            }                                                                \
        }                                                                    \
    }

    // ---- g layer 1 (K=16) ----
    {
        half8 xb[2];
        #pragma unroll
        for (int rg = 0; rg < 2; ++rg) {
            const float* xp = &x[(size_t)(row0 + rg * 32 + l31) * 32 + lk * 8];
            #pragma unroll
            for (int kk = 0; kk < 8; ++kk) xb[rg][kk] = (_Float16)xp[kk];
        }
        #pragma unroll
        for (int nt = 0; nt < 2; ++nt) {
            half8 wb = *(const half8*)&ws[GW1OFF + ((wv * 2 + nt) * 64 + l) * 8];
            #pragma unroll
            for (int rg = 0; rg < 2; ++rg) {
                #pragma unroll
                for (int r = 0; r < 16; ++r)
                    acc[nt][rg][r] =
                        gb1[n0 + nt * 32 + (r & 3) + 8 * (r >> 2) + 4 * lk];
                acc[nt][rg] = MFMA16(wb, xb[rg], acc[nt][rg], 0, 0, 0);
            }
        }
    }
    G_EPI();
    __syncthreads();

    // ---- g layers 2..4 (2-deep pipeline + setprio) ----
#define G_LA(ks, A_)                                                         \
    { A_[0] = *(const half8*)&sA[((ks) * 64 + l) * 8];                       \
      A_[1] = *(const half8*)&sA[((64 + (ks)) * 64 + l) * 8]; }
#define G_LB(ks, B_)                                                         \
    { const int _o = (ks) * 16384 + wv * 1024 + l * 8;                       \
      B_[0] = *(const half8*)&W[_o];                                         \
      B_[1] = *(const half8*)&W[_o + 512]; }
#define G_MM(A_, B_)                                                         \
    { __builtin_amdgcn_s_setprio(1);                                         \
      acc[0][0] = MFMA16(B_[0], A_[0], acc[0][0], 0, 0, 0);                  \
      acc[0][1] = MFMA16(B_[0], A_[1], acc[0][1], 0, 0, 0);                  \
      acc[1][0] = MFMA16(B_[1], A_[0], acc[1][0], 0, 0, 0);                  \
      acc[1][1] = MFMA16(B_[1], A_[1], acc[1][1], 0, 0, 0);                  \
      __builtin_amdgcn_s_setprio(0); }

    #pragma unroll 1
    for (int L = 0; L < 3; ++L) {
        const _Float16* W = ws + (size_t)L * MWH;

        half8 A0[2], A1[2], B0[2], B1[2];
        G_LA(0, A0); G_LB(0, B0);
        G_LA(1, A1); G_LB(1, B1);

        #pragma unroll
        for (int nt = 0; nt < 2; ++nt)
            #pragma unroll
            for (int rg = 0; rg < 2; ++rg)
                #pragma unroll
                for (int r = 0; r < 16; ++r)
                    acc[nt][rg][r] =
                        s_bias[L][n0 + nt * 32 + (r & 3) + 8 * (r >> 2) + 4 * lk];

        #pragma unroll 1
        for (int ks = 0; ks < 64; ks += 2) {
            G_MM(A0, B0);
            if (ks + 2 < 64) { G_LA(ks + 2, A0); G_LB(ks + 2, B0); }
            G_MM(A1, B1);
            if (ks + 3 < 64) { G_LA(ks + 3, A1); G_LB(ks + 3, B1); }
        }

        __syncthreads();     // all waves done reading sA
        G_EPI();
        __syncthreads();     // sA ready for next layer
    }
#undef G_LA
#undef G_LB
#undef G_MM
#undef G_EPI

    // ---- g layer 5: out_g[row] = act . gW5 + gb5 ----
    {
        const int row = t & 63;
        const int rg5 = row >> 5, r31 = row & 31;
        const int c = t >> 6;          // 0..15: 64-n chunk
        float s = 0.f;
        #pragma unroll
        for (int q = 0; q < 4; ++q) {
            #pragma unroll
            for (int kh = 0; kh < 2; ++kh) {
                half8 v = *(const half8*)&sA[((rg5 * 64 + c * 4 + q) * 64 +
                                             ((kh << 5) | r31)) * 8];
                const float* w = &s_w5f[(c * 4 + q) * 16 + kh * 8];
                #pragma unroll
                for (int kk = 0; kk < 8; ++kk)
                    s = fmaf((float)v[kk], w[kk], s);
            }
        }
        s_red[t] = s;
    }
    __syncthreads();   // also: all sA reads for g are complete after this
    if (t < 64) {
        float s = gb5[0];
        #pragma unroll
        for (int c = 0; c < 16; ++c) s += s_red[c * 64 + t];
        out[(size_t)B_ROWS * D_NETS + row0 + t] = s;
    }

    // ======================= fused h-net: wave wv = net wv ==================
    // acts in sN = sA[wv*4096 .. +4096): layout [rg2][ks4][lane64][8k]
    {
        _Float16* sN = &sA[wv * 4096];
        const _Float16* hp = ws + HPOFF + (size_t)wv * 3 * 4096;
        const int rgl = l >> 5;

        // ---- h layer 1: lane l owns row l ----
        {
            const float x2 = x[(size_t)(row0 + l) * 32 + 16 + wv];
            const float* w1 = &hW1[wv * 64];
            const float* b1 = &hb1[wv * 64];
            #pragma unroll
            for (int ks = 0; ks < 4; ++ks) {
                #pragma unroll
                for (int kh = 0; kh < 2; ++kh) {
                    half8 v;
                    #pragma unroll
                    for (int kk = 0; kk < 8; ++kk) {
                        const int j = ks * 16 + kh * 8 + kk;
                        v[kk] = (_Float16)fmaxf(fmaf(x2, w1[j], b1[j]), 0.f);
                    }
                    *(half8*)&sN[((rgl * 4 + ks) * 64 + ((kh << 5) | l31)) * 8] = v;
                }
            }
        }

        // ---- h layers 2..4: 16 MFMAs each, wave-local ----
        #pragma unroll 1
        for (int L = 0; L < 3; ++L) {
            const _Float16* W = hp + (size_t)L * 4096;
            const float* hbL = ((L == 0) ? hb2 : (L == 1) ? hb3 : hb4) + wv * 64;

            #pragma unroll
            for (int ng = 0; ng < 2; ++ng)
                #pragma unroll
                for (int rg = 0; rg < 2; ++rg)
                    #pragma unroll
                    for (int r = 0; r < 16; ++r)
                        acc[ng][rg][r] =
                            hbL[ng * 32 + (r & 3) + 8 * (r >> 2) + 4 * lk];

            #pragma unroll
            for (int ks = 0; ks < 4; ++ks) {
                half8 w0 = *(const half8*)&W[((ks * 2 + 0) * 64 + l) * 8];
                half8 w1_ = *(const half8*)&W[((ks * 2 + 1) * 64 + l) * 8];
                half8 a0 = *(const half8*)&sN[((0 * 4 + ks) * 64 + l) * 8];
                half8 a1 = *(const half8*)&sN[((1 * 4 + ks) * 64 + l) * 8];
                acc[0][0] = MFMA16(w0, a0, acc[0][0], 0, 0, 0);
                acc[0][1] = MFMA16(w0, a1, acc[0][1], 0, 0, 0);
                acc[1][0] = MFMA16(w1_, a0, acc[1][0], 0, 0, 0);
                acc[1][1] = MFMA16(w1_, a1, acc[1][1], 0, 0, 0);
            }

            // epilogue (same q->(ks,kh,kk0) math as g, 4-ks local space)
            #pragma unroll
            for (int ng = 0; ng < 2; ++ng)
                #pragma unroll
                for (int rg = 0; rg < 2; ++rg)
                    #pragma unroll
                    for (int q = 0; q < 4; ++q) {
                        half4 v;
                        #pragma unroll
                        for (int j = 0; j < 4; ++j)
                            v[j] = (_Float16)fmaxf(acc[ng][rg][q * 4 + j], 0.f);
                        const int ksn = ng * 2 + (q >> 1);
                        const int li  = ((q & 1) << 5) | l31;
                        *(half4*)&sN[((rg * 4 + ksn) * 64 + li) * 8 + lk * 4] = v;
                    }
        }

        // ---- h layer 5: lane l owns row l ----
        {
            const float* w5 = &hW5[wv * 64];
            float s = 0.f;
            #pragma unroll
            for (int ks = 0; ks < 4; ++ks) {
                #pragma unroll
                for (int kh = 0; kh < 2; ++kh) {
                    half8 v = *(const half8*)&sN[((rgl * 4 + ks) * 64 +
                                                 ((kh << 5) | l31)) * 8];
                    const float* w = &w5[ks * 16 + kh * 8];
                    #pragma unroll
                    for (int kk = 0; kk < 8; ++kk)
                        s = fmaf((float)v[kk], w[kk], s);
                }
            }
            out[(size_t)(row0 + l) * 16 + wv] = s + hb5[wv];
        }
    }
}

extern "C" void kernel_launch(void* const* d_in, const int* in_sizes, int n_in,
                              void* d_out, int out_size, void* d_ws, size_t ws_size,
                              hipStream_t stream) {
    (void)in_sizes; (void)n_in; (void)out_size; (void)ws_size;

    const float* x   = (const float*)d_in[0];
    const float* hW1 = (const float*)d_in[1];
    const float* hb1 = (const float*)d_in[2];
    const float* hW2 = (const float*)d_in[3];
    const float* hb2 = (const float*)d_in[4];
    const float* hW3 = (const float*)d_in[5];
    const float* hb3 = (const float*)d_in[6];
    const float* hW4 = (const float*)d_in[7];
    const float* hb4 = (const float*)d_in[8];
    const float* hW5 = (const float*)d_in[9];
    const float* hb5 = (const float*)d_in[10];
    const float* gW1 = (const float*)d_in[11];
    const float* gb1 = (const float*)d_in[12];
    const float* gW2 = (const float*)d_in[13];
    const float* gb2 = (const float*)d_in[14];
    const float* gW3 = (const float*)d_in[15];
    const float* gb3 = (const float*)d_in[16];
    const float* gW4 = (const float*)d_in[17];
    const float* gb4 = (const float*)d_in[18];
    const float* gW5 = (const float*)d_in[19];
    const float* gb5 = (const float*)d_in[20];
    float* out = (float*)d_out;
    _Float16* wsh = (_Float16*)d_ws;

    pack_f16<<<1640, 256, 0, stream>>>(gW1, gW2, gW3, gW4, hW2, hW3, hW4, wsh);

    g_fused_v7<<<B_ROWS / 64, 1024, 0, stream>>>(
        x, wsh, gb1, gb2, gb3, gb4, gW5, gb5,
        hW1, hb1, hb2, hb3, hb4, hW5, hb5, out);
}

// Round 13
// 247.742 us; speedup vs baseline: 1.5771x; 1.0163x over previous
//
#include <hip/hip_runtime.h>

#define B_ROWS 32768
#define D_NETS 16
#define MWH    1048576              // halfs per packed 1024x1024 layer
#define GW1OFF (3 * MWH)            // gW1 pack offset (halfs)
#define HPOFF  (GW1OFF + 16384)     // h-net pack offset (halfs)

typedef _Float16 half8 __attribute__((ext_vector_type(8)));
typedef _Float16 half4 __attribute__((ext_vector_type(4)));
typedef __attribute__((ext_vector_type(16))) float f32x16;

#define MFMA16 __builtin_amdgcn_mfma_f32_32x32x16_f16

// ---------------------------------------------------------------------------
// pack: all weights -> fp16, MFMA-fragment-linear packed (A-operand layout:
// lane = khalf*32 + (n&31), 8 consecutive k per lane).
// ---------------------------------------------------------------------------
__global__ void pack_f16(const float* __restrict__ gW1,
                         const float* __restrict__ gW2,
                         const float* __restrict__ gW3,
                         const float* __restrict__ gW4,
                         const float* __restrict__ hW2,
                         const float* __restrict__ hW3,
                         const float* __restrict__ hW4,
                         _Float16* __restrict__ ws) {
    const int p = blockIdx.x * 256 + threadIdx.x;
    const float* src;
    size_t dst;
    if (p < 393216) {                       // gW2/3/4: 3 x 131072 chunks
        const int lz = p >> 17;
        const int pl = p & 131071;
        const float* W = (lz == 0) ? gW2 : (lz == 1) ? gW3 : gW4;
        const int l = pl & 63, g = (pl >> 6) & 31, ks = pl >> 11;
        src = &W[(size_t)(g * 32 + (l & 31)) * 1024 + ks * 16 + (l >> 5) * 8];
        dst = (size_t)lz * MWH + (size_t)pl * 8;
    } else if (p < 395264) {                // gW1: 2048 chunks
        const int q = p - 393216;
        const int l = q & 63, g = q >> 6;
        src = &gW1[(g * 32 + (l & 31)) * 16 + (l >> 5) * 8];
        dst = GW1OFF + (size_t)q * 8;
    } else {                                // hW2/3/4: 24576 chunks
        const int q = p - 395264;
        const int l = q & 63;
        const int sub = (q >> 6) & 7;       // ks*2+g
        const int ks = sub >> 1, g = sub & 1;
        const int dL = q >> 9;              // d*3+L
        const int d = dL / 3, L = dL - d * 3;
        const float* W = (L == 0) ? hW2 : (L == 1) ? hW3 : hW4;
        src = &W[d * 4096 + (g * 32 + (l & 31)) * 64 + ks * 16 + (l >> 5) * 8];
        dst = HPOFF + (size_t)q * 8;
    }
    half8 v;
    #pragma unroll
    for (int kk = 0; kk < 8; ++kk) v[kk] = (_Float16)src[kk];
    *(half8*)&ws[dst] = v;
}

// ---------------------------------------------------------------------------
// g + h fused (v8). g part = proven v6. h tail changes vs v7:
//  - separate hacc registers (decouple scheduling regions / lifetimes)
//  - x2 load hoisted (issued right after last main barrier, used in tail)
//  - h outputs staged in s_red -> one coalesced 4KB block write
// ---------------------------------------------------------------------------
__global__ __launch_bounds__(1024, 4) void g_fused_v8(
    const float* __restrict__ x,
    const _Float16* __restrict__ ws,
    const float* __restrict__ gb1, const float* __restrict__ gb2,
    const float* __restrict__ gb3, const float* __restrict__ gb4,
    const float* __restrict__ gW5, const float* __restrict__ gb5,
    const float* __restrict__ hW1, const float* __restrict__ hb1,
    const float* __restrict__ hb2, const float* __restrict__ hb3,
    const float* __restrict__ hb4,
    const float* __restrict__ hW5, const float* __restrict__ hb5,
    float* __restrict__ out)
{
    __shared__ _Float16 sA[65536];     // 128 KiB act pack
    __shared__ float s_w5f[1024];
    __shared__ float s_red[1024];
    __shared__ float s_bias[3][1024];  // gb2/gb3/gb4

    const int t = threadIdx.x;
    const int l = t & 63, wv = t >> 6;
    const int l31 = l & 31, lk = l >> 5;
    const int n0 = wv * 64;
    const int row0 = blockIdx.x * 64;

    s_w5f[t] = gW5[t];
    s_bias[0][t] = gb2[t];
    s_bias[1][t] = gb3[t];
    s_bias[2][t] = gb4[t];

    f32x16 acc[2][2];   // [nt][rg]

#define G_EPI()                                                              \
    {                                                                        \
        _Pragma("unroll")                                                    \
        for (int nt = 0; nt < 2; ++nt) {                                     \
            _Pragma("unroll")                                                \
            for (int rg = 0; rg < 2; ++rg) {                                 \
                _Pragma("unroll")                                            \
                for (int q = 0; q < 4; ++q) {                                \
                    half4 v;                                                 \
                    _Pragma("unroll")                                        \
                    for (int j = 0; j < 4; ++j)                              \
                        v[j] = (_Float16)fmaxf(acc[nt][rg][q * 4 + j], 0.f); \
                    const int ksn = wv * 4 + nt * 2 + (q >> 1);              \
                    const int li  = ((q & 1) << 5) | l31;                    \
                    *(half4*)&sA[((rg * 64 + ksn) * 64 + li) * 8 + lk * 4] = v; \
                }                                                            \
            }                                                                \
        }                                                                    \
    }

    // ---- g layer 1 (K=16) ----
    {
        half8 xb[2];
        #pragma unroll
        for (int rg = 0; rg < 2; ++rg) {
            const float* xp = &x[(size_t)(row0 + rg * 32 + l31) * 32 + lk * 8];
            #pragma unroll
            for (int kk = 0; kk < 8; ++kk) xb[rg][kk] = (_Float16)xp[kk];
        }
        #pragma unroll
        for (int nt = 0; nt < 2; ++nt) {
            half8 wb = *(const half8*)&ws[GW1OFF + ((wv * 2 + nt) * 64 + l) * 8];
            #pragma unroll
            for (int rg = 0; rg < 2; ++rg) {
                #pragma unroll
                for (int r = 0; r < 16; ++r)
                    acc[nt][rg][r] =
                        gb1[n0 + nt * 32 + (r & 3) + 8 * (r >> 2) + 4 * lk];
                acc[nt][rg] = MFMA16(wb, xb[rg], acc[nt][rg], 0, 0, 0);
            }
        }
    }
    G_EPI();
    __syncthreads();

    // ---- g layers 2..4 (2-deep pipeline + setprio) ----
#define G_LA(ks, A_)                                                         \
    { A_[0] = *(const half8*)&sA[((ks) * 64 + l) * 8];                       \
      A_[1] = *(const half8*)&sA[((64 + (ks)) * 64 + l) * 8]; }
#define G_LB(ks, B_)                                                         \
    { const int _o = (ks) * 16384 + wv * 1024 + l * 8;                       \
      B_[0] = *(const half8*)&W[_o];                                         \
      B_[1] = *(const half8*)&W[_o + 512]; }
#define G_MM(A_, B_)                                                         \
    { __builtin_amdgcn_s_setprio(1);                                         \
      acc[0][0] = MFMA16(B_[0], A_[0], acc[0][0], 0, 0, 0);                  \
      acc[0][1] = MFMA16(B_[0], A_[1], acc[0][1], 0, 0, 0);                  \
      acc[1][0] = MFMA16(B_[1], A_[0], acc[1][0], 0, 0, 0);                  \
      acc[1][1] = MFMA16(B_[1], A_[1], acc[1][1], 0, 0, 0);                  \
      __builtin_amdgcn_s_setprio(0); }

    #pragma unroll 1
    for (int L = 0; L < 3; ++L) {
        const _Float16* W = ws + (size_t)L * MWH;

        half8 A0[2], A1[2], B0[2], B1[2];
        G_LA(0, A0); G_LB(0, B0);
        G_LA(1, A1); G_LB(1, B1);

        #pragma unroll
        for (int nt = 0; nt < 2; ++nt)
            #pragma unroll
            for (int rg = 0; rg < 2; ++rg)
                #pragma unroll
                for (int r = 0; r < 16; ++r)
                    acc[nt][rg][r] =
                        s_bias[L][n0 + nt * 32 + (r & 3) + 8 * (r >> 2) + 4 * lk];

        #pragma unroll 1
        for (int ks = 0; ks < 64; ks += 2) {
            G_MM(A0, B0);
            if (ks + 2 < 64) { G_LA(ks + 2, A0); G_LB(ks + 2, B0); }
            G_MM(A1, B1);
            if (ks + 3 < 64) { G_LA(ks + 3, A1); G_LB(ks + 3, B1); }
        }

        __syncthreads();     // all waves done reading sA
        G_EPI();
        __syncthreads();     // sA ready for next layer
    }
#undef G_LA
#undef G_LB
#undef G_MM
#undef G_EPI

    // hoisted h input load: issue now, use after g L5 (latency hides under L5)
    const float x2 = x[(size_t)(row0 + l) * 32 + 16 + wv];

    // ---- g layer 5: out_g[row] = act . gW5 + gb5 ----
    {
        const int row = t & 63;
        const int rg5 = row >> 5, r31 = row & 31;
        const int c = t >> 6;          // 0..15: 64-n chunk
        float s = 0.f;
        #pragma unroll
        for (int q = 0; q < 4; ++q) {
            #pragma unroll
            for (int kh = 0; kh < 2; ++kh) {
                half8 v = *(const half8*)&sA[((rg5 * 64 + c * 4 + q) * 64 +
                                             ((kh << 5) | r31)) * 8];
                const float* w = &s_w5f[(c * 4 + q) * 16 + kh * 8];
                #pragma unroll
                for (int kk = 0; kk < 8; ++kk)
                    s = fmaf((float)v[kk], w[kk], s);
            }
        }
        s_red[t] = s;
    }
    __syncthreads();   // also: all sA reads for g are complete after this
    if (t < 64) {
        float s = gb5[0];
        #pragma unroll
        for (int c = 0; c < 16; ++c) s += s_red[c * 64 + t];
        out[(size_t)B_ROWS * D_NETS + row0 + t] = s;
    }
    __syncthreads();   // s_red free for h output staging

    // ======================= fused h-net: wave wv = net wv ==================
    // acts in sN = sA[wv*4096 .. +4096): layout [rg2][ks4][lane64][8k]
    {
        _Float16* sN = &sA[wv * 4096];
        const _Float16* hp = ws + HPOFF + (size_t)wv * 3 * 4096;
        const int rgl = l >> 5;

        // ---- h layer 1: lane l owns row l (x2 preloaded above) ----
        {
            const float* w1 = &hW1[wv * 64];
            const float* b1 = &hb1[wv * 64];
            #pragma unroll
            for (int ks = 0; ks < 4; ++ks) {
                #pragma unroll
                for (int kh = 0; kh < 2; ++kh) {
                    half8 v;
                    #pragma unroll
                    for (int kk = 0; kk < 8; ++kk) {
                        const int j = ks * 16 + kh * 8 + kk;
                        v[kk] = (_Float16)fmaxf(fmaf(x2, w1[j], b1[j]), 0.f);
                    }
                    *(half8*)&sN[((rgl * 4 + ks) * 64 + ((kh << 5) | l31)) * 8] = v;
                }
            }
        }

        // ---- h layers 2..4: 16 MFMAs each, wave-local; separate hacc ----
        f32x16 hacc[2][2];
        #pragma unroll 1
        for (int L = 0; L < 3; ++L) {
            const _Float16* W = hp + (size_t)L * 4096;
            const float* hbL = ((L == 0) ? hb2 : (L == 1) ? hb3 : hb4) + wv * 64;

            #pragma unroll
            for (int ng = 0; ng < 2; ++ng)
                #pragma unroll
                for (int rg = 0; rg < 2; ++rg)
                    #pragma unroll
                    for (int r = 0; r < 16; ++r)
                        hacc[ng][rg][r] =
                            hbL[ng * 32 + (r & 3) + 8 * (r >> 2) + 4 * lk];

            #pragma unroll
            for (int ks = 0; ks < 4; ++ks) {
                half8 w0 = *(const half8*)&W[((ks * 2 + 0) * 64 + l) * 8];
                half8 w1_ = *(const half8*)&W[((ks * 2 + 1) * 64 + l) * 8];
                half8 a0 = *(const half8*)&sN[((0 * 4 + ks) * 64 + l) * 8];
                half8 a1 = *(const half8*)&sN[((1 * 4 + ks) * 64 + l) * 8];
                hacc[0][0] = MFMA16(w0, a0, hacc[0][0], 0, 0, 0);
                hacc[0][1] = MFMA16(w0, a1, hacc[0][1], 0, 0, 0);
                hacc[1][0] = MFMA16(w1_, a0, hacc[1][0], 0, 0, 0);
                hacc[1][1] = MFMA16(w1_, a1, hacc[1][1], 0, 0, 0);
            }

            #pragma unroll
            for (int ng = 0; ng < 2; ++ng)
                #pragma unroll
                for (int rg = 0; rg < 2; ++rg)
                    #pragma unroll
                    for (int q = 0; q < 4; ++q) {
                        half4 v;
                        #pragma unroll
                        for (int j = 0; j < 4; ++j)
                            v[j] = (_Float16)fmaxf(hacc[ng][rg][q * 4 + j], 0.f);
                        const int ksn = ng * 2 + (q >> 1);
                        const int li  = ((q & 1) << 5) | l31;
                        *(half4*)&sN[((rg * 4 + ksn) * 64 + li) * 8 + lk * 4] = v;
                    }
        }

        // ---- h layer 5: lane l owns row l; stage to s_red ----
        {
            const float* w5 = &hW5[wv * 64];
            float s = 0.f;
            #pragma unroll
            for (int ks = 0; ks < 4; ++ks) {
                #pragma unroll
                for (int kh = 0; kh < 2; ++kh) {
                    half8 v = *(const half8*)&sN[((rgl * 4 + ks) * 64 +
                                                 ((kh << 5) | l31)) * 8];
                    const float* w = &w5[ks * 16 + kh * 8];
                    #pragma unroll
                    for (int kk = 0; kk < 8; ++kk)
                        s = fmaf((float)v[kk], w[kk], s);
                }
            }
            s_red[l * 16 + wv] = s + hb5[wv];
        }
    }
    __syncthreads();
    // coalesced h output: 64 rows x 16 d = 4 KB contiguous ([row][d] layout)
    if (t < 1024) {
        const int row = t >> 4, d = t & 15;
        out[(size_t)(row0 + row) * 16 + d] = s_red[row * 16 + d];
    }
}

extern "C" void kernel_launch(void* const* d_in, const int* in_sizes, int n_in,
                              void* d_out, int out_size, void* d_ws, size_t ws_size,
                              hipStream_t stream) {
    (void)in_sizes; (void)n_in; (void)out_size; (void)ws_size;

    const float* x   = (const float*)d_in[0];
    const float* hW1 = (const float*)d_in[1];
    const float* hb1 = (const float*)d_in[2];
    const float* hW2 = (const float*)d_in[3];
    const float* hb2 = (const float*)d_in[4];
    const float* hW3 = (const float*)d_in[5];
    const float* hb3 = (const float*)d_in[6];
    const float* hW4 = (const float*)d_in[7];
    const float* hb4 = (const float*)d_in[8];
    const float* hW5 = (const float*)d_in[9];
    const float* hb5 = (const float*)d_in[10];
    const float* gW1 = (const float*)d_in[11];
    const float* gb1 = (const float*)d_in[12];
    const float* gW2 = (const float*)d_in[13];
    const float* gb2 = (const float*)d_in[14];
    const float* gW3 = (const float*)d_in[15];
    const float* gb3 = (const float*)d_in[16];
    const float* gW4 = (const float*)d_in[17];
    const float* gb4 = (const float*)d_in[18];
    const float* gW5 = (const float*)d_in[19];
    const float* gb5 = (const float*)d_in[20];
    float* out = (float*)d_out;
    _Float16* wsh = (_Float16*)d_ws;

    pack_f16<<<1640, 256, 0, stream>>>(gW1, gW2, gW3, gW4, hW2, hW3, hW4, wsh);

    g_fused_v8<<<B_ROWS / 64, 1024, 0, stream>>>(
        x, wsh, gb1, gb2, gb3, gb4, gW5, gb5,
        hW1, hb1, hb2, hb3, hb4, hW5, hb5, out);
}